// Round 14
// baseline (282.330 us; speedup 1.0000x reference)
//
#include <hip/hip_runtime.h>
#include <hip/hip_fp8.h>

#define Nn 40000
#define Ee 600000
#define Hh 128
#define Gg 32
#define Cc 6
#define CAP 64                   // ELL slots per node (mean deg 15, +12 sigma; fixed input)
#define NT (Nn / 16)             // 2500 layer tiles
#define LSTR 136                 // LDS A-tile row stride (u16)
#define PADW 0x9C409C40u         // two u16 pad indices (Nn = 40000 = 0x9C40)
#define NBIN 16
#define BINCAP 40960             // per-bin edge capacity (mean 37500, +18 sigma)

typedef __bf16 bf16x8 __attribute__((ext_vector_type(8)));
typedef float floatx4 __attribute__((ext_vector_type(4)));
typedef float floatx2 __attribute__((ext_vector_type(2)));
typedef unsigned short u16;
typedef unsigned int u32;
typedef unsigned char u8;

__device__ __forceinline__ u16 f2b(float f) {
    union { float f; u32 i; } v; v.f = f;
    u32 r = v.i + 0x7fffu + ((v.i >> 16) & 1u);   // RNE
    return (u16)(r >> 16);
}
__device__ __forceinline__ u32 pack2(float a, float b) {
    return (u32)f2b(a) | ((u32)f2b(b) << 16);
}
// fp8 e4m3 (OCP) encode for the one-shot setup cast
__device__ __forceinline__ u8 f8e(float f) {
    __hip_fp8_e4m3 v(f); return (u8)v.__x;
}
// HW single-value encode for layer epilogues (RNE, OCP e4m3)
__device__ __forceinline__ u8 f8e_hw(float f) {
    return (u8)(__builtin_amdgcn_cvt_pk_fp8_f32(f, f, 0, false) & 0xff);
}

// ---------------- setup + castpack merged: zero cursor/emb/gbin, prefill colidx=pads (u16),
// zero pad rows, pack 7 weight matrices into MFMA B-frag order, cast x -> bf16 + fp8 rows ----------------
__global__ __launch_bounds__(256) void k_setup(int* cursor, float* emb, int* gbin,
                                               u16* xb, u16* hA16, u8* xf8, u8* hA8, u8* hB8,
                                               float* dinv, u16* colidx,
                                               const float* __restrict__ x,
                                               const float* w0, const float* w1, const float* w2,
                                               const float* w3, const float* w4, const float* w5,
                                               const float* w6, u16* __restrict__ pwdst) {
    int gid = blockIdx.x * 256 + threadIdx.x;
    if (gid < Nn) cursor[gid] = 0;
    if (gid < Gg * Hh) emb[gid] = 0.f;
    if (gid < NBIN) gbin[gid] = 0;
    if (blockIdx.x == 0) {
        int t = threadIdx.x;
        uint4 z = { 0, 0, 0, 0 };
        if (t < 16)              *(uint4*)(xb  + (size_t)Nn * 128 + t * 8) = z;
        else if (t < 32)         *(uint4*)(hA16 + (size_t)Nn * 128 + (t - 16) * 8) = z;
        else if (t < 40)         *(uint4*)(xf8 + (size_t)Nn * 128 + (t - 32) * 16) = z;
        else if (t < 48)         *(uint4*)(hA8 + (size_t)Nn * 128 + (t - 40) * 16) = z;
        else if (t < 56)         *(uint4*)(hB8 + (size_t)Nn * 128 + (t - 48) * 16) = z;
        else if (t == 56)        dinv[Nn] = 0.f;
    }
    if (blockIdx.x < 448) {
        int idx = gid;
        if (idx < 7 * 16384) {
            const float* ws[7] = { w0, w1, w2, w3, w4, w5, w6 };
            int mat = idx >> 14, r = idx & 16383;
            int j = r & 7, n = (r >> 3) & 15, q = (r >> 7) & 3, nt = (r >> 9) & 7, t = r >> 12;
            pwdst[idx] = f2b(ws[mat][(t * 32 + q * 8 + j) * 128 + nt * 16 + n]);
        }
    } else {
        int gid2 = (blockIdx.x - 448) * 256 + threadIdx.x;   // 0 .. 1,279,999
        int i = gid2 * 4;                                    // covers Nn*128 = 5.12M exactly
        float4 v = *(const float4*)(x + i);
        ushort4 o = { f2b(v.x), f2b(v.y), f2b(v.z), f2b(v.w) };
        *(ushort4*)(xb + i) = o;
        u32 p8 = (u32)f8e(v.x) | ((u32)f8e(v.y) << 8) | ((u32)f8e(v.z) << 16) | ((u32)f8e(v.w) << 24);
        *(u32*)(xf8 + i) = p8;
        *(u32*)(colidx + gid2 * 2) = PADW;                   // prefill ELL pads: 1.28M u32 = 2.56M u16 slots
    }
}

// ---------------- R28 k_bin: bucket edges into 16 dst-range bins (packed u32 = src | dst<<16) -------------
// Mechanism: scatter's cost is cross-XCD line ping-pong on colidx RMW stores (u16 round halved it).
// Binning makes all stores to a dst-region issue from one XCD class in k_scatter2.
__global__ __launch_bounds__(256) void k_bin(const int* __restrict__ src, const int* __restrict__ dst,
                                             int* __restrict__ gbin, u32* __restrict__ ebuf,
                                             int* __restrict__ cursor, u16* __restrict__ colidx) {
    __shared__ int cnt[NBIN];
    __shared__ int base[NBIN];
    int tid = threadIdx.x;
    int i = blockIdx.x * 256 + tid;
    if (tid < NBIN) cnt[tid] = 0;
    __syncthreads();
    int bin = -1, myslot = 0, s = 0, d = 0;
    if (i < Ee) {
        s = src[i];
        d = dst[i];
        bin = d / 2500;                       // 40000/16 = 2500 -> bins 0..15
        myslot = atomicAdd(&cnt[bin], 1);
    }
    __syncthreads();
    if (tid < NBIN) base[tid] = (cnt[tid] > 0) ? atomicAdd(&gbin[tid], cnt[tid]) : 0;
    __syncthreads();
    if (bin >= 0) {
        int slot = base[bin] + myslot;
        if (slot < BINCAP) {
            ebuf[bin * BINCAP + slot] = (u32)s | ((u32)d << 16);
        } else {
            // overflow fallback: direct scatter (keeps correctness; statistically never taken)
            int p = atomicAdd(&cursor[d], 1);
            if (p < CAP) colidx[d * CAP + p] = (u16)s;
        }
    }
}

// ---------------- R28 k_scatter2: bins -> ELL, XCD-affine (blockIdx%8 = bin class) --------------------
// All stores to bin b's colidx region issue from blocks of class b%8 (observed round-robin
// block->XCD mapping) -> RMW stays L2-local, no cross-XCD bounce. ONE atomic = position AND degree.
__global__ __launch_bounds__(256) void k_scatter2(const u32* __restrict__ ebuf, const int* __restrict__ gbin,
                                                  int* __restrict__ cursor, u16* __restrict__ colidx) {
    int cls = blockIdx.x & 7;
    int idx = blockIdx.x >> 3;
    int nidx = gridDim.x >> 3;
    for (int b = cls; b < NBIN; b += 8) {
        int n = gbin[b]; if (n > BINCAP) n = BINCAP;
        const u32* eb = ebuf + b * BINCAP;
        for (int e = idx * 256 + threadIdx.x; e < n; e += nidx * 256) {
            u32 p = eb[e];
            int d = p >> 16, s = p & 0xFFFFu;
            int pos = atomicAdd(&cursor[d], 1);
            if (pos < CAP) colidx[d * CAP + pos] = (u16)s;
        }
    }
}

// ---------------- FUSED layer: fp8 gather-agg (ELL u16 stream, inline pdeg) -> LDS bf16 -> MFMA GEMM ------
// pdeg inline from cursor[node]; layer 1 (wrdinv) writes dinv[node] — complete at the L1/L2 kernel
// boundary, two boundaries before GCN layer 3 reads it. One uint4 = 8 edge indices.
// R25 lesson: do NOT merge k_final here.
#define UPC_ADD(V) { floatx2 p_;                                                          \
    p_ = __builtin_amdgcn_cvt_pk_f32_fp8((int)(V).x, false); a0 += p_.x; a1 += p_.y;      \
    p_ = __builtin_amdgcn_cvt_pk_f32_fp8((int)(V).x, true);  a2 += p_.x; a3 += p_.y;      \
    p_ = __builtin_amdgcn_cvt_pk_f32_fp8((int)(V).y, false); a4 += p_.x; a5 += p_.y;      \
    p_ = __builtin_amdgcn_cvt_pk_f32_fp8((int)(V).y, true);  a6 += p_.x; a7 += p_.y; }

#define UPC_FMA(V, d) { floatx2 p_;                                                                 \
    p_ = __builtin_amdgcn_cvt_pk_f32_fp8((int)(V).x, false); a0 += (d) * p_.x; a1 += (d) * p_.y;    \
    p_ = __builtin_amdgcn_cvt_pk_f32_fp8((int)(V).x, true);  a2 += (d) * p_.x; a3 += (d) * p_.y;    \
    p_ = __builtin_amdgcn_cvt_pk_f32_fp8((int)(V).y, false); a4 += (d) * p_.x; a5 += (d) * p_.y;    \
    p_ = __builtin_amdgcn_cvt_pk_f32_fp8((int)(V).y, true);  a6 += (d) * p_.x; a7 += (d) * p_.y; }

__global__ __launch_bounds__(256) void k_layer(const u8* __restrict__ hin8,
                                               const u16* __restrict__ hin16,
                                               const u16* __restrict__ Bp_agg,
                                               const u16* __restrict__ Bp_self,
                                               const float* __restrict__ bias,
                                               u16* __restrict__ hout16,
                                               u8* __restrict__ hout8,
                                               const int* __restrict__ cursor,
                                               const u16* __restrict__ pcol,
                                               float* __restrict__ dinv,
                                               const int* __restrict__ batch,
                                               float* __restrict__ emb,
                                               int gcn, int relu, int dopool, int wrdinv) {
    __shared__ u16 Asm[16 * LSTR];
    __shared__ float Psm[16][132];
    int wave = threadIdx.x >> 6, lane = threadIdx.x & 63;
    int m0 = blockIdx.x * 16;

    // ---- phase A: 8 row-gathers in flight per 16-lane group (ELL row, u16 indices) ----
    {
        int g = lane >> 4, l = lane & 15;
        int nloc = wave * 4 + g;
        int node = m0 + nloc;
        int c = cursor[node]; if (c > CAP) c = CAP;
        if (wrdinv && l == 0) dinv[node] = rsqrtf((float)(c + 1));
        int beg = node * CAP;
        int end = beg + ((c + 7) & ~7);
        float a0 = 0.f, a1 = 0.f, a2 = 0.f, a3 = 0.f, a4 = 0.f, a5 = 0.f, a6 = 0.f, a7 = 0.f;
        const u8* b8 = hin8 + l * 8;
        if (beg < end) {
            uint4 ip = *(const uint4*)(pcol + beg);   // 8 u16 indices
            if (gcn) {
                for (int e = beg; e < end; e += 8) {
                    int en = (e + 8 < end) ? (e + 8) : beg;
                    uint4 jp = *(const uint4*)(pcol + en);
                    u32 e0 = ip.x & 0xFFFFu, e1 = ip.x >> 16;
                    u32 e2 = ip.y & 0xFFFFu, e3 = ip.y >> 16;
                    u32 e4 = ip.z & 0xFFFFu, e5 = ip.z >> 16;
                    u32 e6 = ip.w & 0xFFFFu, e7 = ip.w >> 16;
                    float d0 = dinv[e0], d1 = dinv[e1], d2 = dinv[e2], d3 = dinv[e3];
                    float d4 = dinv[e4], d5 = dinv[e5], d6 = dinv[e6], d7 = dinv[e7];
                    uint2 v0 = *(const uint2*)(b8 + (size_t)e0 * 128);
                    uint2 v1 = *(const uint2*)(b8 + (size_t)e1 * 128);
                    uint2 v2 = *(const uint2*)(b8 + (size_t)e2 * 128);
                    uint2 v3 = *(const uint2*)(b8 + (size_t)e3 * 128);
                    uint2 v4 = *(const uint2*)(b8 + (size_t)e4 * 128);
                    uint2 v5 = *(const uint2*)(b8 + (size_t)e5 * 128);
                    uint2 v6 = *(const uint2*)(b8 + (size_t)e6 * 128);
                    uint2 v7 = *(const uint2*)(b8 + (size_t)e7 * 128);
                    UPC_FMA(v0, d0) UPC_FMA(v1, d1) UPC_FMA(v2, d2) UPC_FMA(v3, d3)
                    UPC_FMA(v4, d4) UPC_FMA(v5, d5) UPC_FMA(v6, d6) UPC_FMA(v7, d7)
                    ip = jp;
                }
            } else {
                for (int e = beg; e < end; e += 8) {
                    int en = (e + 8 < end) ? (e + 8) : beg;
                    uint4 jp = *(const uint4*)(pcol + en);
                    u32 e0 = ip.x & 0xFFFFu, e1 = ip.x >> 16;
                    u32 e2 = ip.y & 0xFFFFu, e3 = ip.y >> 16;
                    u32 e4 = ip.z & 0xFFFFu, e5 = ip.z >> 16;
                    u32 e6 = ip.w & 0xFFFFu, e7 = ip.w >> 16;
                    uint2 v0 = *(const uint2*)(b8 + (size_t)e0 * 128);
                    uint2 v1 = *(const uint2*)(b8 + (size_t)e1 * 128);
                    uint2 v2 = *(const uint2*)(b8 + (size_t)e2 * 128);
                    uint2 v3 = *(const uint2*)(b8 + (size_t)e3 * 128);
                    uint2 v4 = *(const uint2*)(b8 + (size_t)e4 * 128);
                    uint2 v5 = *(const uint2*)(b8 + (size_t)e5 * 128);
                    uint2 v6 = *(const uint2*)(b8 + (size_t)e6 * 128);
                    uint2 v7 = *(const uint2*)(b8 + (size_t)e7 * 128);
                    UPC_ADD(v0) UPC_ADD(v1) UPC_ADD(v2) UPC_ADD(v3)
                    UPC_ADD(v4) UPC_ADD(v5) UPC_ADD(v6) UPC_ADD(v7)
                    ip = jp;
                }
            }
        }
        if (gcn) {
            float di = dinv[node], d2n = di * di;
            uint2 us = *(const uint2*)(b8 + (size_t)node * 128);
            a0 *= di; a1 *= di; a2 *= di; a3 *= di;
            a4 *= di; a5 *= di; a6 *= di; a7 *= di;
            UPC_FMA(us, d2n)
        }
        uint4 o = { pack2(a0, a1), pack2(a2, a3), pack2(a4, a5), pack2(a6, a7) };
        *(uint4*)&Asm[nloc * LSTR + l * 8] = o;
    }
    __syncthreads();

    // ---- phase B: 16-row GEMM; wave handles cols [wave*32, wave*32+32) ----
    {
        int n = lane & 15, q = lane >> 4;
        floatx4 acc0 = (floatx4){0.f, 0.f, 0.f, 0.f};
        floatx4 acc1 = (floatx4){0.f, 0.f, 0.f, 0.f};
        int nt0 = wave * 2, nt1 = wave * 2 + 1;
#pragma unroll
        for (int t = 0; t < 4; t++) {
            bf16x8 a = *(const bf16x8*)&Asm[n * LSTR + q * 8 + t * 32];
            const u16* bp = Bp_agg + t * 4096 + q * 128 + n * 8;
            bf16x8 b0 = *(const bf16x8*)(bp + nt0 * 512);
            bf16x8 b1 = *(const bf16x8*)(bp + nt1 * 512);
            acc0 = __builtin_amdgcn_mfma_f32_16x16x32_bf16(a, b0, acc0, 0, 0, 0);
            acc1 = __builtin_amdgcn_mfma_f32_16x16x32_bf16(a, b1, acc1, 0, 0, 0);
        }
        if (!gcn) {
            const u16* arow = hin16 + (size_t)(m0 + n) * 128 + q * 8;
#pragma unroll
            for (int t = 0; t < 4; t++) {
                bf16x8 a = *(const bf16x8*)(arow + t * 32);
                const u16* bp = Bp_self + t * 4096 + q * 128 + n * 8;
                bf16x8 b0 = *(const bf16x8*)(bp + nt0 * 512);
                bf16x8 b1 = *(const bf16x8*)(bp + nt1 * 512);
                acc0 = __builtin_amdgcn_mfma_f32_16x16x32_bf16(a, b0, acc0, 0, 0, 0);
                acc1 = __builtin_amdgcn_mfma_f32_16x16x32_bf16(a, b1, acc1, 0, 0, 0);
            }
        }
        if (dopool) {
#pragma unroll
            for (int j = 0; j < 2; j++) {
                int col = (wave * 2 + j) * 16 + n;
                float bv = bias[col];
                floatx4 ac = j ? acc1 : acc0;
#pragma unroll
                for (int r = 0; r < 4; r++)
                    Psm[q * 4 + r][col] = ac[r] + bv;
            }
            __syncthreads();
            if (threadIdx.x < 128) {
                int col = threadIdx.x;
                int g0 = batch[m0], g1 = batch[m0 + 15];
                for (int g = g0; g <= g1; ++g) {
                    float s = 0.f;
#pragma unroll
                    for (int i = 0; i < 16; ++i)
                        if (batch[m0 + i] == g) s += Psm[i][col];
                    atomicAdd(&emb[g * 128 + col], s);
                }
            }
        } else {
#pragma unroll
            for (int j = 0; j < 2; j++) {
                int col = (wave * 2 + j) * 16 + n;
                float bv = bias[col];
                floatx4 ac = j ? acc1 : acc0;
#pragma unroll
                for (int r = 0; r < 4; r++) {
                    float v = ac[r] + bv;
                    if (relu) v = fmaxf(v, 0.f);
                    size_t idx = (size_t)(m0 + q * 4 + r) * 128 + col;
                    if (hout16) hout16[idx] = f2b(v);
                    if (hout8)  hout8[idx]  = f8e_hw(v);
                }
            }
        }
    }
}

// ---------------- final: gcnt via binary search (batch sorted) + embedding + logits (f32 out) ----------------
// Separate 1-block kernel with PLAIN cached loads — R25 proved merging this into layer 5 costs ~200 µs.
__global__ __launch_bounds__(256) void k_final(const float* __restrict__ emb, const int* __restrict__ batch,
                                               const float* __restrict__ lw, const float* __restrict__ lb,
                                               float* __restrict__ out) {
    __shared__ float cnt[Gg];
    int t = threadIdx.x;
    if (t < Gg) {
        int lo = 0, hi = Nn;
        while (lo < hi) { int m = (lo + hi) >> 1; if (batch[m] < t) lo = m + 1; else hi = m; }
        int lb0 = lo;
        lo = 0; hi = Nn;
        int tg = t + 1;
        while (lo < hi) { int m = (lo + hi) >> 1; if (batch[m] < tg) lo = m + 1; else hi = m; }
        cnt[t] = fmaxf((float)(lo - lb0), 1.f);
    }
    __syncthreads();
    for (int i = t; i < Gg * Hh; i += 256) {
        int g = i >> 7;
        out[Gg * Cc + i] = emb[i] / cnt[g];
    }
    if (t < Gg * Cc) {
        int g = t / Cc, c = t % Cc;
        float cn = cnt[g];
        float s = lb[c];
        for (int f = 0; f < Hh; f++)
            s += (emb[g * 128 + f] / cn) * lw[f * Cc + c];
        out[t] = s;
    }
}

extern "C" void kernel_launch(void* const* d_in, const int* in_sizes, int n_in,
                              void* d_out, int out_size, void* d_ws, size_t ws_size,
                              hipStream_t stream) {
    const float* x       = (const float*)d_in[0];
    const int*   ei      = (const int*)d_in[1];
    const int*   batch   = (const int*)d_in[2];
    const float* w1_root = (const float*)d_in[3];
    const float* w1_rel  = (const float*)d_in[4];
    const float* b1      = (const float*)d_in[5];
    const float* w2_root = (const float*)d_in[6];
    const float* w2_rel  = (const float*)d_in[7];
    const float* b2      = (const float*)d_in[8];
    const float* w3      = (const float*)d_in[9];
    const float* b3      = (const float*)d_in[10];
    const float* w4      = (const float*)d_in[11];
    const float* b4      = (const float*)d_in[12];
    const float* w5      = (const float*)d_in[13];
    const float* b5      = (const float*)d_in[14];
    const float* lw      = (const float*)d_in[15];
    const float* lb      = (const float*)d_in[16];
    const int* srcp = ei;
    const int* dstp = ei + Ee;
    float* out = (float*)d_out;

    char* w = (char*)d_ws;
    size_t off = 0;
    auto alloc = [&](size_t bytes) { size_t r = off; off += (bytes + 255) & ~(size_t)255; return r; };
    int*   cursor  = (int*)(w + alloc(Nn * 4));                     // scatter cursor -> degrees
    u16*   colidx  = (u16*)(w + alloc((size_t)Nn * CAP * 2));       // ELL u16: node*CAP + slot
    u32*   ebuf    = (u32*)(w + alloc((size_t)NBIN * BINCAP * 4));  // binned packed edges
    int*   gbin    = (int*)(w + alloc(256));                        // per-bin cursors
    float* dinv    = (float*)(w + alloc((Nn + 1) * 4));             // written by layer 1; dinv[Nn]=0
    float* emb     = (float*)(w + alloc(Gg * Hh * 4));
    u16*   pw      = (u16*)(w + alloc(7 * 16384 * 2));
    u16*   xb      = (u16*)(w + alloc((size_t)(Nn + 1) * Hh * 2));  // bf16 x (+1 zero row)
    u16*   hA16    = (u16*)(w + alloc((size_t)(Nn + 1) * Hh * 2));  // bf16 L1 out (L2 self-GEMM)
    u8*    xf8     = (u8*)(w + alloc((size_t)(Nn + 1) * Hh));       // fp8 gather tables (+1 zero row)
    u8*    hA8     = (u8*)(w + alloc((size_t)(Nn + 1) * Hh));
    u8*    hB8     = (u8*)(w + alloc((size_t)(Nn + 1) * Hh));
    (void)ws_size;

    u16* pw1r = pw + 0 * 16384;
    u16* pw1l = pw + 1 * 16384;
    u16* pw2r = pw + 2 * 16384;
    u16* pw2l = pw + 3 * 16384;
    u16* pw3  = pw + 4 * 16384;
    u16* pw4  = pw + 5 * 16384;
    u16* pw5  = pw + 6 * 16384;
    const u16* nil16 = (const u16*)nullptr;
    u16* no16 = (u16*)nullptr;
    u8*  no8  = (u8*)nullptr;

    // preprocessing: 3 launches (setup prefills u16 ELL pads; bin -> XCD-affine scatter)
    hipLaunchKernelGGL(k_setup, dim3(448 + Nn * Hh / 1024), dim3(256), 0, stream,
                       cursor, emb, gbin, xb, hA16, xf8, hA8, hB8, dinv, colidx,
                       x, w1_root, w1_rel, w2_root, w2_rel, w3, w4, w5, pw);
    hipLaunchKernelGGL(k_bin, dim3((Ee + 255) / 256), dim3(256), 0, stream,
                       srcp, dstp, gbin, ebuf, cursor, colidx);
    hipLaunchKernelGGL(k_scatter2, dim3(2048), dim3(256), 0, stream,
                       ebuf, gbin, cursor, colidx);

    // fused layers (block = 16 nodes, 2500 blocks); fp8 ping-pong xf8 -> hA8 -> hB8 -> hA8 -> xf8;
    // layer 1 writes dinv. 9 dispatches total.
    hipLaunchKernelGGL(k_layer, dim3(NT), dim3(256), 0, stream,
                       xf8, xb, pw1l, pw1r, b1, hA16, hA8, cursor, colidx, dinv, batch, emb, 0, 1, 0, 1);
    hipLaunchKernelGGL(k_layer, dim3(NT), dim3(256), 0, stream,
                       hA8, hA16, pw2l, pw2r, b2, no16, hB8, cursor, colidx, dinv, batch, emb, 0, 1, 0, 0);
    hipLaunchKernelGGL(k_layer, dim3(NT), dim3(256), 0, stream,
                       hB8, nil16, pw3, nil16, b3, no16, hA8, cursor, colidx, dinv, batch, emb, 1, 1, 0, 0);
    hipLaunchKernelGGL(k_layer, dim3(NT), dim3(256), 0, stream,
                       hA8, nil16, pw4, nil16, b4, no16, xf8, cursor, colidx, dinv, batch, emb, 1, 1, 0, 0);
    hipLaunchKernelGGL(k_layer, dim3(NT), dim3(256), 0, stream,
                       xf8, nil16, pw5, nil16, b5, no16, no8, cursor, colidx, dinv, batch, emb, 1, 0, 1, 0);

    // final linear + embedding output (gcnt via binary search)
    hipLaunchKernelGGL(k_final, dim3(1), dim3(256), 0, stream, emb, batch, lw, lb, out);
}

// Round 15
// 247.944 us; speedup vs baseline: 1.1387x; 1.1387x over previous
//
#include <hip/hip_runtime.h>
#include <hip/hip_fp8.h>

#define Nn 40000
#define Ee 600000
#define Hh 128
#define Gg 32
#define Cc 6
#define CAP 64                   // ELL slots per node (mean deg 15, +12 sigma; fixed input)
#define NT (Nn / 16)             // 2500 layer tiles
#define LSTR 136                 // LDS A-tile row stride (u16)
#define PADW 0x9C409C40u         // two u16 pad indices (Nn = 40000 = 0x9C40)

typedef __bf16 bf16x8 __attribute__((ext_vector_type(8)));
typedef float floatx4 __attribute__((ext_vector_type(4)));
typedef float floatx2 __attribute__((ext_vector_type(2)));
typedef unsigned short u16;
typedef unsigned int u32;
typedef unsigned char u8;

__device__ __forceinline__ u16 f2b(float f) {
    union { float f; u32 i; } v; v.f = f;
    u32 r = v.i + 0x7fffu + ((v.i >> 16) & 1u);   // RNE
    return (u16)(r >> 16);
}
__device__ __forceinline__ u32 pack2(float a, float b) {
    return (u32)f2b(a) | ((u32)f2b(b) << 16);
}
// fp8 e4m3 (OCP) encode for the one-shot setup cast
__device__ __forceinline__ u8 f8e(float f) {
    __hip_fp8_e4m3 v(f); return (u8)v.__x;
}
// HW single-value encode for layer epilogues (RNE, OCP e4m3)
__device__ __forceinline__ u8 f8e_hw(float f) {
    return (u8)(__builtin_amdgcn_cvt_pk_fp8_f32(f, f, 0, false) & 0xff);
}

// ---------------- setup + castpack merged: zero cursor/emb, prefill colidx=pads (u16),
// zero pad rows, pack 7 weight matrices into MFMA B-frag order, cast x -> bf16 + fp8 rows ----------------
__global__ __launch_bounds__(256) void k_setup(int* cursor, float* emb,
                                               u16* xb, u16* hA16, u8* xf8, u8* hA8, u8* hB8,
                                               float* dinv, u16* colidx,
                                               const float* __restrict__ x,
                                               const float* w0, const float* w1, const float* w2,
                                               const float* w3, const float* w4, const float* w5,
                                               const float* w6, u16* __restrict__ pwdst) {
    int gid = blockIdx.x * 256 + threadIdx.x;
    if (gid < Nn) cursor[gid] = 0;
    if (gid < Gg * Hh) emb[gid] = 0.f;
    if (blockIdx.x == 0) {
        int t = threadIdx.x;
        uint4 z = { 0, 0, 0, 0 };
        if (t < 16)              *(uint4*)(xb  + (size_t)Nn * 128 + t * 8) = z;
        else if (t < 32)         *(uint4*)(hA16 + (size_t)Nn * 128 + (t - 16) * 8) = z;
        else if (t < 40)         *(uint4*)(xf8 + (size_t)Nn * 128 + (t - 32) * 16) = z;
        else if (t < 48)         *(uint4*)(hA8 + (size_t)Nn * 128 + (t - 40) * 16) = z;
        else if (t < 56)         *(uint4*)(hB8 + (size_t)Nn * 128 + (t - 48) * 16) = z;
        else if (t == 56)        dinv[Nn] = 0.f;
    }
    if (blockIdx.x < 448) {
        int idx = gid;
        if (idx < 7 * 16384) {
            const float* ws[7] = { w0, w1, w2, w3, w4, w5, w6 };
            int mat = idx >> 14, r = idx & 16383;
            int j = r & 7, n = (r >> 3) & 15, q = (r >> 7) & 3, nt = (r >> 9) & 7, t = r >> 12;
            pwdst[idx] = f2b(ws[mat][(t * 32 + q * 8 + j) * 128 + nt * 16 + n]);
        }
    } else {
        int gid2 = (blockIdx.x - 448) * 256 + threadIdx.x;   // 0 .. 1,279,999
        int i = gid2 * 4;                                    // covers Nn*128 = 5.12M exactly
        float4 v = *(const float4*)(x + i);
        ushort4 o = { f2b(v.x), f2b(v.y), f2b(v.z), f2b(v.w) };
        *(ushort4*)(xb + i) = o;
        u32 p8 = (u32)f8e(v.x) | ((u32)f8e(v.y) << 8) | ((u32)f8e(v.z) << 16) | ((u32)f8e(v.w) << 24);
        *(u32*)(xf8 + i) = p8;
        *(u32*)(colidx + gid2 * 2) = PADW;                   // prefill ELL pads: 1.28M u32 = 2.56M u16 slots
    }
}

// ---------------- ELL scatter (R27 proven form, 1 edge/thread): ONE atomic = position AND degree ----------
// Tested and closed: 4-edge batching (R23/24 neutral-negative), XCD-affine binning (R28 -30 µs).
// u16 stores (R27, -15 µs) kept. ~30 µs is this kernel's floor.
__global__ __launch_bounds__(256) void k_scatter(const int* __restrict__ src, const int* __restrict__ dst,
                                                 int* __restrict__ cursor, u16* __restrict__ colidx) {
    int i = blockIdx.x * 256 + threadIdx.x;
    if (i < Ee) {
        int d = dst[i];
        int p = atomicAdd(&cursor[d], 1);
        if (p < CAP) colidx[d * CAP + p] = (u16)src[i];
    }
}

// ---------------- FUSED layer: fp8 gather-agg (ELL u16, pre-scaled GCN inputs) -> LDS bf16 -> MFMA GEMM ---
// R29: GCN inputs are stored PRE-SCALED (h*dinv, applied in the producer's epilogue via scale8), so
// GCN phase A = the same plain-ADD loop as GraphConv + self-row add + one multiply by dinv[node]:
//   out_i = dinv_i * [ sum_j stored_j + stored_i ],  stored = h*dinv.
// Removes 600k random dinv[e] loads per GCN layer. pdeg inline from cursor[node]; layer 1 (wrdinv)
// writes dinv[node] — complete at the L1/L2 boundary. R25 lesson: do NOT merge k_final here.
#define UPC_ADD(V) { floatx2 p_;                                                          \
    p_ = __builtin_amdgcn_cvt_pk_f32_fp8((int)(V).x, false); a0 += p_.x; a1 += p_.y;      \
    p_ = __builtin_amdgcn_cvt_pk_f32_fp8((int)(V).x, true);  a2 += p_.x; a3 += p_.y;      \
    p_ = __builtin_amdgcn_cvt_pk_f32_fp8((int)(V).y, false); a4 += p_.x; a5 += p_.y;      \
    p_ = __builtin_amdgcn_cvt_pk_f32_fp8((int)(V).y, true);  a6 += p_.x; a7 += p_.y; }

__global__ __launch_bounds__(256) void k_layer(const u8* __restrict__ hin8,
                                               const u16* __restrict__ hin16,
                                               const u16* __restrict__ Bp_agg,
                                               const u16* __restrict__ Bp_self,
                                               const float* __restrict__ bias,
                                               u16* __restrict__ hout16,
                                               u8* __restrict__ hout8,
                                               const int* __restrict__ cursor,
                                               const u16* __restrict__ pcol,
                                               float* __restrict__ dinv,
                                               const int* __restrict__ batch,
                                               float* __restrict__ emb,
                                               int gcn, int relu, int dopool, int wrdinv, int scale8) {
    __shared__ u16 Asm[16 * LSTR];
    __shared__ float Psm[16][132];
    int wave = threadIdx.x >> 6, lane = threadIdx.x & 63;
    int m0 = blockIdx.x * 16;

    // ---- phase A: 8 row-gathers in flight per 16-lane group (unified ADD loop) ----
    {
        int g = lane >> 4, l = lane & 15;
        int nloc = wave * 4 + g;
        int node = m0 + nloc;
        int c = cursor[node]; if (c > CAP) c = CAP;
        if (wrdinv && l == 0) dinv[node] = rsqrtf((float)(c + 1));
        int beg = node * CAP;
        int end = beg + ((c + 7) & ~7);
        float a0 = 0.f, a1 = 0.f, a2 = 0.f, a3 = 0.f, a4 = 0.f, a5 = 0.f, a6 = 0.f, a7 = 0.f;
        const u8* b8 = hin8 + l * 8;
        if (beg < end) {
            uint4 ip = *(const uint4*)(pcol + beg);   // 8 u16 indices
            for (int e = beg; e < end; e += 8) {
                int en = (e + 8 < end) ? (e + 8) : beg;
                uint4 jp = *(const uint4*)(pcol + en);
                u32 e0 = ip.x & 0xFFFFu, e1 = ip.x >> 16;
                u32 e2 = ip.y & 0xFFFFu, e3 = ip.y >> 16;
                u32 e4 = ip.z & 0xFFFFu, e5 = ip.z >> 16;
                u32 e6 = ip.w & 0xFFFFu, e7 = ip.w >> 16;
                uint2 v0 = *(const uint2*)(b8 + (size_t)e0 * 128);
                uint2 v1 = *(const uint2*)(b8 + (size_t)e1 * 128);
                uint2 v2 = *(const uint2*)(b8 + (size_t)e2 * 128);
                uint2 v3 = *(const uint2*)(b8 + (size_t)e3 * 128);
                uint2 v4 = *(const uint2*)(b8 + (size_t)e4 * 128);
                uint2 v5 = *(const uint2*)(b8 + (size_t)e5 * 128);
                uint2 v6 = *(const uint2*)(b8 + (size_t)e6 * 128);
                uint2 v7 = *(const uint2*)(b8 + (size_t)e7 * 128);
                UPC_ADD(v0) UPC_ADD(v1) UPC_ADD(v2) UPC_ADD(v3)
                UPC_ADD(v4) UPC_ADD(v5) UPC_ADD(v6) UPC_ADD(v7)
                ip = jp;
            }
        }
        if (gcn) {
            uint2 us = *(const uint2*)(b8 + (size_t)node * 128);   // stored_i = h_i * dinv_i
            UPC_ADD(us)
            float di = dinv[node];
            a0 *= di; a1 *= di; a2 *= di; a3 *= di;
            a4 *= di; a5 *= di; a6 *= di; a7 *= di;
        }
        uint4 o = { pack2(a0, a1), pack2(a2, a3), pack2(a4, a5), pack2(a6, a7) };
        *(uint4*)&Asm[nloc * LSTR + l * 8] = o;
    }
    __syncthreads();

    // ---- phase B: 16-row GEMM; wave handles cols [wave*32, wave*32+32) ----
    {
        int n = lane & 15, q = lane >> 4;
        floatx4 acc0 = (floatx4){0.f, 0.f, 0.f, 0.f};
        floatx4 acc1 = (floatx4){0.f, 0.f, 0.f, 0.f};
        int nt0 = wave * 2, nt1 = wave * 2 + 1;
#pragma unroll
        for (int t = 0; t < 4; t++) {
            bf16x8 a = *(const bf16x8*)&Asm[n * LSTR + q * 8 + t * 32];
            const u16* bp = Bp_agg + t * 4096 + q * 128 + n * 8;
            bf16x8 b0 = *(const bf16x8*)(bp + nt0 * 512);
            bf16x8 b1 = *(const bf16x8*)(bp + nt1 * 512);
            acc0 = __builtin_amdgcn_mfma_f32_16x16x32_bf16(a, b0, acc0, 0, 0, 0);
            acc1 = __builtin_amdgcn_mfma_f32_16x16x32_bf16(a, b1, acc1, 0, 0, 0);
        }
        if (!gcn) {
            const u16* arow = hin16 + (size_t)(m0 + n) * 128 + q * 8;
#pragma unroll
            for (int t = 0; t < 4; t++) {
                bf16x8 a = *(const bf16x8*)(arow + t * 32);
                const u16* bp = Bp_self + t * 4096 + q * 128 + n * 8;
                bf16x8 b0 = *(const bf16x8*)(bp + nt0 * 512);
                bf16x8 b1 = *(const bf16x8*)(bp + nt1 * 512);
                acc0 = __builtin_amdgcn_mfma_f32_16x16x32_bf16(a, b0, acc0, 0, 0, 0);
                acc1 = __builtin_amdgcn_mfma_f32_16x16x32_bf16(a, b1, acc1, 0, 0, 0);
            }
        }
        if (dopool) {
#pragma unroll
            for (int j = 0; j < 2; j++) {
                int col = (wave * 2 + j) * 16 + n;
                float bv = bias[col];
                floatx4 ac = j ? acc1 : acc0;
#pragma unroll
                for (int r = 0; r < 4; r++)
                    Psm[q * 4 + r][col] = ac[r] + bv;
            }
            __syncthreads();
            if (threadIdx.x < 128) {
                int col = threadIdx.x;
                int g0 = batch[m0], g1 = batch[m0 + 15];
                for (int g = g0; g <= g1; ++g) {
                    float s = 0.f;
#pragma unroll
                    for (int i = 0; i < 16; ++i)
                        if (batch[m0 + i] == g) s += Psm[i][col];
                    atomicAdd(&emb[g * 128 + col], s);
                }
            }
        } else {
            float sc[4];
#pragma unroll
            for (int r = 0; r < 4; r++)
                sc[r] = scale8 ? dinv[m0 + q * 4 + r] : 1.f;
#pragma unroll
            for (int j = 0; j < 2; j++) {
                int col = (wave * 2 + j) * 16 + n;
                float bv = bias[col];
                floatx4 ac = j ? acc1 : acc0;
#pragma unroll
                for (int r = 0; r < 4; r++) {
                    float v = ac[r] + bv;
                    if (relu) v = fmaxf(v, 0.f);
                    size_t idx = (size_t)(m0 + q * 4 + r) * 128 + col;
                    if (hout16) hout16[idx] = f2b(v);
                    if (hout8)  hout8[idx]  = f8e_hw(v * sc[r]);
                }
            }
        }
    }
}

// ---------------- final: gcnt via binary search (batch sorted) + embedding + logits (f32 out) ----------------
// Separate 1-block kernel with PLAIN cached loads — R25 proved merging this into layer 5 costs ~200 µs.
__global__ __launch_bounds__(256) void k_final(const float* __restrict__ emb, const int* __restrict__ batch,
                                               const float* __restrict__ lw, const float* __restrict__ lb,
                                               float* __restrict__ out) {
    __shared__ float cnt[Gg];
    int t = threadIdx.x;
    if (t < Gg) {
        int lo = 0, hi = Nn;
        while (lo < hi) { int m = (lo + hi) >> 1; if (batch[m] < t) lo = m + 1; else hi = m; }
        int lb0 = lo;
        lo = 0; hi = Nn;
        int tg = t + 1;
        while (lo < hi) { int m = (lo + hi) >> 1; if (batch[m] < tg) lo = m + 1; else hi = m; }
        cnt[t] = fmaxf((float)(lo - lb0), 1.f);
    }
    __syncthreads();
    for (int i = t; i < Gg * Hh; i += 256) {
        int g = i >> 7;
        out[Gg * Cc + i] = emb[i] / cnt[g];
    }
    if (t < Gg * Cc) {
        int g = t / Cc, c = t % Cc;
        float cn = cnt[g];
        float s = lb[c];
        for (int f = 0; f < Hh; f++)
            s += (emb[g * 128 + f] / cn) * lw[f * Cc + c];
        out[t] = s;
    }
}

extern "C" void kernel_launch(void* const* d_in, const int* in_sizes, int n_in,
                              void* d_out, int out_size, void* d_ws, size_t ws_size,
                              hipStream_t stream) {
    const float* x       = (const float*)d_in[0];
    const int*   ei      = (const int*)d_in[1];
    const int*   batch   = (const int*)d_in[2];
    const float* w1_root = (const float*)d_in[3];
    const float* w1_rel  = (const float*)d_in[4];
    const float* b1      = (const float*)d_in[5];
    const float* w2_root = (const float*)d_in[6];
    const float* w2_rel  = (const float*)d_in[7];
    const float* b2      = (const float*)d_in[8];
    const float* w3      = (const float*)d_in[9];
    const float* b3      = (const float*)d_in[10];
    const float* w4      = (const float*)d_in[11];
    const float* b4      = (const float*)d_in[12];
    const float* w5      = (const float*)d_in[13];
    const float* b5      = (const float*)d_in[14];
    const float* lw      = (const float*)d_in[15];
    const float* lb      = (const float*)d_in[16];
    const int* srcp = ei;
    const int* dstp = ei + Ee;
    float* out = (float*)d_out;

    char* w = (char*)d_ws;
    size_t off = 0;
    auto alloc = [&](size_t bytes) { size_t r = off; off += (bytes + 255) & ~(size_t)255; return r; };
    int*   cursor  = (int*)(w + alloc(Nn * 4));                     // scatter cursor -> degrees
    u16*   colidx  = (u16*)(w + alloc((size_t)Nn * CAP * 2));       // ELL u16: node*CAP + slot
    float* dinv    = (float*)(w + alloc((Nn + 1) * 4));             // written by layer 1; dinv[Nn]=0
    float* emb     = (float*)(w + alloc(Gg * Hh * 4));
    u16*   pw      = (u16*)(w + alloc(7 * 16384 * 2));
    u16*   xb      = (u16*)(w + alloc((size_t)(Nn + 1) * Hh * 2));  // bf16 x (+1 zero row)
    u16*   hA16    = (u16*)(w + alloc((size_t)(Nn + 1) * Hh * 2));  // bf16 L1 out (L2 self-GEMM)
    u8*    xf8     = (u8*)(w + alloc((size_t)(Nn + 1) * Hh));       // fp8 gather tables (+1 zero row)
    u8*    hA8     = (u8*)(w + alloc((size_t)(Nn + 1) * Hh));
    u8*    hB8     = (u8*)(w + alloc((size_t)(Nn + 1) * Hh));
    (void)ws_size;

    u16* pw1r = pw + 0 * 16384;
    u16* pw1l = pw + 1 * 16384;
    u16* pw2r = pw + 2 * 16384;
    u16* pw2l = pw + 3 * 16384;
    u16* pw3  = pw + 4 * 16384;
    u16* pw4  = pw + 5 * 16384;
    u16* pw5  = pw + 6 * 16384;
    const u16* nil16 = (const u16*)nullptr;
    u16* no16 = (u16*)nullptr;
    u8*  no8  = (u8*)nullptr;

    // preprocessing: 2 launches (setup prefills u16 ELL pads; scatter's atomic doubles as degree)
    hipLaunchKernelGGL(k_setup, dim3(448 + Nn * Hh / 1024), dim3(256), 0, stream,
                       cursor, emb, xb, hA16, xf8, hA8, hB8, dinv, colidx,
                       x, w1_root, w1_rel, w2_root, w2_rel, w3, w4, w5, pw);
    hipLaunchKernelGGL(k_scatter, dim3((Ee + 255) / 256), dim3(256), 0, stream,
                       srcp, dstp, cursor, colidx);

    // fused layers (block = 16 nodes, 2500 blocks); fp8 ping-pong xf8 -> hA8 -> hB8 -> hA8 -> xf8;
    // layer 1 writes dinv; layers 2-4 store fp8 outputs PRE-SCALED by dinv (scale8) for GCN consumers.
    hipLaunchKernelGGL(k_layer, dim3(NT), dim3(256), 0, stream,
                       xf8, xb, pw1l, pw1r, b1, hA16, hA8, cursor, colidx, dinv, batch, emb,
                       0, 1, 0, 1, 0);
    hipLaunchKernelGGL(k_layer, dim3(NT), dim3(256), 0, stream,
                       hA8, hA16, pw2l, pw2r, b2, no16, hB8, cursor, colidx, dinv, batch, emb,
                       0, 1, 0, 0, 1);
    hipLaunchKernelGGL(k_layer, dim3(NT), dim3(256), 0, stream,
                       hB8, nil16, pw3, nil16, b3, no16, hA8, cursor, colidx, dinv, batch, emb,
                       1, 1, 0, 0, 1);
    hipLaunchKernelGGL(k_layer, dim3(NT), dim3(256), 0, stream,
                       hA8, nil16, pw4, nil16, b4, no16, xf8, cursor, colidx, dinv, batch, emb,
                       1, 1, 0, 0, 1);
    hipLaunchKernelGGL(k_layer, dim3(NT), dim3(256), 0, stream,
                       xf8, nil16, pw5, nil16, b5, no16, no8, cursor, colidx, dinv, batch, emb,
                       1, 0, 1, 0, 0);

    // final linear + embedding output (gcnt via binary search)
    hipLaunchKernelGGL(k_final, dim3(1), dim3(256), 0, stream, emb, batch, lw, lb, out);
}